// Round 5
// baseline (1753.767 us; speedup 1.0000x reference)
//
#include <hip/hip_runtime.h>

#define NU 50000
#define NI 100000
#define NN 150000
#define NE 2400000
#define DD 64
#define NL 3
#define CHUNK 1024
#define NB ((NN + CHUNK - 1) / CHUNK)   // 147 scan blocks

// ---- init: ego = concat(user_emb, item_emb); out[:, 0:64] = ego (layer-0, un-normalized)
__global__ void init_kernel(const float* __restrict__ uemb, const float* __restrict__ iemb,
                            float* __restrict__ ego, float* __restrict__ out) {
    int i = blockIdx.x * blockDim.x + threadIdx.x;
    if (i >= NN * DD) return;
    int n = i >> 6, d = i & 63;
    float v = (n < NU) ? uemb[i] : iemb[i - NU * DD];
    ego[i] = v;
    out[n * (DD * (NL + 1)) + d] = v;
}

// ---- CSR build: histogram of dst + per-edge rank (the atomic's return value,
// which fill would otherwise have to re-derive with a second atomic round-trip)
__global__ void hist_kernel(const int* __restrict__ dst, int* __restrict__ counts,
                            unsigned short* __restrict__ rank) {
    int e = blockIdx.x * blockDim.x + threadIdx.x;
    if (e < NE) {
        int r = atomicAdd(&counts[dst[e]], 1);
        rank[e] = (unsigned short)r;   // mean degree 16; 65535 cap unreachable
    }
}

// ---- scan stage A: per-block (1024-elem chunk) totals
__global__ void scanA_kernel(const int* __restrict__ counts, int* __restrict__ bsum) {
    __shared__ int sh[256];
    int t = threadIdx.x, b = blockIdx.x;
    int base = b * CHUNK + t * 4;
    int s = 0;
#pragma unroll
    for (int i = 0; i < 4; ++i) { int idx = base + i; if (idx < NN) s += counts[idx]; }
    sh[t] = s; __syncthreads();
    for (int off = 128; off > 0; off >>= 1) {
        if (t < off) sh[t] += sh[t + off];
        __syncthreads();
    }
    if (t == 0) bsum[b] = sh[0];
}

// ---- scan stage B: exclusive scan of the NB(=147) block sums, one block
__global__ void scanB_kernel(int* __restrict__ bsum, int* __restrict__ offs) {
    __shared__ int sh[256];
    int t = threadIdx.x;
    int v = (t < NB) ? bsum[t] : 0;
    sh[t] = v; __syncthreads();
    for (int off = 1; off < 256; off <<= 1) {
        int add = (t >= off) ? sh[t - off] : 0;
        __syncthreads();
        sh[t] += add;
        __syncthreads();
    }
    if (t < NB) bsum[t] = sh[t] - v;          // exclusive block offset
    if (t == NB - 1) offs[NN] = sh[t];        // total == NE
}

// ---- scan stage C: full exclusive scan -> offs
__global__ void scanC_kernel(const int* __restrict__ counts, const int* __restrict__ bsum,
                             int* __restrict__ offs) {
    __shared__ int sh[256];
    int t = threadIdx.x, b = blockIdx.x;
    int base = b * CHUNK + t * 4;
    int c[4]; int tsum = 0;
#pragma unroll
    for (int i = 0; i < 4; ++i) { int idx = base + i; c[i] = (idx < NN) ? counts[idx] : 0; tsum += c[i]; }
    sh[t] = tsum; __syncthreads();
    for (int off = 1; off < 256; off <<= 1) {
        int add = (t >= off) ? sh[t - off] : 0;
        __syncthreads();
        sh[t] += add;
        __syncthreads();
    }
    int excl = sh[t] - tsum + bsum[b];
#pragma unroll
    for (int i = 0; i < 4; ++i) {
        int idx = base + i;
        if (idx < NN) offs[idx] = excl;
        excl += c[i];
    }
}

// ---- CSR fill: atomic-free. pos = offs[dst] + rank (rank captured in hist).
// Pure sequential reads + one scatter store; no TCC round-trip dependency.
__global__ void fill_kernel(const int* __restrict__ src, const int* __restrict__ dst,
                            const float* __restrict__ vals, const int* __restrict__ offs,
                            const unsigned short* __restrict__ rank, int2* __restrict__ pair) {
    int e = blockIdx.x * blockDim.x + threadIdx.x;
    if (e >= NE) return;
    int d = dst[e];
    int pos = offs[d] + (int)rank[e];
    pair[pos] = make_int2(src[e], __float_as_int(vals[e]));
}

// ---- gather SpMM: one wave per node; 4 edges per iteration, float4 per lane.
// Pair loads for iteration i+1 are issued before iteration i's row gathers,
// breaking the pair-load -> dependent-gather serial chain.
__global__ __launch_bounds__(256) void spmm_kernel(
        const int* __restrict__ offs, const int2* __restrict__ pair,
        const float* __restrict__ ego, float* __restrict__ side) {
    int gid = blockIdx.x * blockDim.x + threadIdx.x;
    int node = gid >> 6;
    if (node >= NN) return;
    int lane = threadIdx.x & 63;
    int sub = lane >> 4;       // which of the 4 edges
    int dq  = lane & 15;       // which dim-quad of the row
    int beg = offs[node], end = offs[node + 1];
    float4 acc = make_float4(0.f, 0.f, 0.f, 0.f);
    if (beg < end) {
        int idx0 = beg + sub;
        int2 p = pair[idx0 < end ? idx0 : end - 1];
        for (int i = beg; i < end; i += 4) {
            int2 pn = p;
            int ni = i + 4;
            if (ni < end) {
                int nidx = ni + sub;
                pn = pair[nidx < end ? nidx : end - 1];   // prefetch next quad
            }
            float w = (i + sub < end) ? __int_as_float(p.y) : 0.f;
            float4 v = ((const float4*)(ego + (size_t)p.x * DD))[dq];
            acc.x = fmaf(w, v.x, acc.x);
            acc.y = fmaf(w, v.y, acc.y);
            acc.z = fmaf(w, v.z, acc.z);
            acc.w = fmaf(w, v.w, acc.w);
            p = pn;
        }
    }
    acc.x += __shfl_xor(acc.x, 16); acc.y += __shfl_xor(acc.y, 16);
    acc.z += __shfl_xor(acc.z, 16); acc.w += __shfl_xor(acc.w, 16);
    acc.x += __shfl_xor(acc.x, 32); acc.y += __shfl_xor(acc.y, 32);
    acc.z += __shfl_xor(acc.z, 32); acc.w += __shfl_xor(acc.w, 32);
    if (sub == 0) ((float4*)(side + (size_t)node * DD))[dq] = acc;
}

// ---- update: W-in-VGPR outer-product.
// Lane j holds {Wg[j][k], Wb[j][k]} in 128 VGPRs. Per wave, 2 node rows are
// staged in LDS as float4 {s0, m0, s1, m1} per k, so the k-loop needs ONE
// uniform-address ds_read_b128 broadcast per k (DS ops halved vs the b64x2
// round-2 layout). Next pair's global loads are issued before the k-loop
// (software pipeline). launch_bounds(256,3): no spill (round-1 lesson).
typedef float v2f __attribute__((ext_vector_type(2)));
#define UPD_TPB 256
#define UPD_GRID 1024
#define NPAIR (NN / 2)          // 75000, exact (no tail)

__global__ __launch_bounds__(UPD_TPB, 3) void update_kernel(
        const float* __restrict__ side, float* __restrict__ ego,
        const float* __restrict__ Wg, const float* __restrict__ bg,
        const float* __restrict__ Wb, const float* __restrict__ bb,
        float* __restrict__ out, int layer) {
    __shared__ float4 sm[UPD_TPB / 64][DD];   // per-wave private: [k] = {s0,m0,s1,m1}
    int tid = threadIdx.x;
    int lane = tid & 63;
    int wid = tid >> 6;

    // lane j's interleaved W rows -> 128 VGPRs
    v2f w[DD];
    {
        const float4* g4 = (const float4*)(Wg + lane * DD);
        const float4* b4 = (const float4*)(Wb + lane * DD);
#pragma unroll
        for (int k4 = 0; k4 < 16; ++k4) {
            float4 a = g4[k4], b = b4[k4];
            w[4 * k4 + 0] = (v2f){a.x, b.x};
            w[4 * k4 + 1] = (v2f){a.y, b.y};
            w[4 * k4 + 2] = (v2f){a.z, b.z};
            w[4 * k4 + 3] = (v2f){a.w, b.w};
        }
    }
    v2f bias = {bg[lane], bb[lane]};

    const int nwaves = UPD_GRID * (UPD_TPB / 64);
    int g = blockIdx.x * (UPD_TPB / 64) + wid;
    if (g >= NPAIR) return;

    // prologue: load first pair's rows (coalesced, lane k holds dim k)
    float s0 = side[(size_t)(2 * g) * DD + lane];
    float s1 = side[(size_t)(2 * g + 1) * DD + lane];
    float e0 = ego[(size_t)(2 * g) * DD + lane];
    float e1 = ego[(size_t)(2 * g + 1) * DD + lane];

    while (true) {
        // stage current pair into LDS as {s0, m0=s0*e0, s1, m1}
        sm[wid][lane] = make_float4(s0, s0 * e0, s1, s1 * e1);

        int gn = g + nwaves;
        bool more = gn < NPAIR;
        int gl = more ? gn : g;   // last iter: harmless dead reload of current
        // issue next pair's loads; latency hides under the k-loop below
        s0 = side[(size_t)(2 * gl) * DD + lane];
        s1 = side[(size_t)(2 * gl + 1) * DD + lane];
        e0 = ego[(size_t)(2 * gl) * DD + lane];
        e1 = ego[(size_t)(2 * gl + 1) * DD + lane];

        v2f acc0 = bias, acc1 = bias;
#pragma unroll 8
        for (int k = 0; k < DD; ++k) {
            float4 q = sm[wid][k];   // uniform-address ds_read_b128 broadcast
            acc0 = __builtin_elementwise_fma((v2f){q.x, q.y}, w[k], acc0);
            acc1 = __builtin_elementwise_fma((v2f){q.z, q.w}, w[k], acc1);
        }

        float ag0 = acc0.x, ab0 = acc0.y, ag1 = acc1.x, ab1 = acc1.y;
        ag0 = (ag0 > 0.f) ? ag0 : 0.01f * ag0;
        ab0 = (ab0 > 0.f) ? ab0 : 0.01f * ab0;
        ag1 = (ag1 > 0.f) ? ag1 : 0.01f * ag1;
        ab1 = (ab1 > 0.f) ? ab1 : 0.01f * ab1;
        float v0 = ag0 + ab0, v1 = ag1 + ab1;
        float sq0 = v0 * v0, sq1 = v1 * v1;
        // two interleaved 64-lane butterfly reductions
#pragma unroll
        for (int off = 1; off < 64; off <<= 1) {
            sq0 += __shfl_xor(sq0, off);
            sq1 += __shfl_xor(sq1, off);
        }
        float r0 = 1.f / fmaxf(sqrtf(sq0), 1e-12f);
        float r1 = 1.f / fmaxf(sqrtf(sq1), 1e-12f);
        int n0 = 2 * g;
        ego[(size_t)n0 * DD + lane] = v0;
        ego[(size_t)(n0 + 1) * DD + lane] = v1;
        out[(size_t)n0 * (DD * (NL + 1)) + (layer + 1) * DD + lane] = v0 * r0;
        out[(size_t)(n0 + 1) * (DD * (NL + 1)) + (layer + 1) * DD + lane] = v1 * r1;

        if (!more) break;
        g = gn;
    }
}

extern "C" void kernel_launch(void* const* d_in, const int* in_sizes, int n_in,
                              void* d_out, int out_size, void* d_ws, size_t ws_size,
                              hipStream_t stream) {
    const int*   edge_src  = (const int*)d_in[0];
    const int*   edge_dst  = (const int*)d_in[1];
    const float* edge_vals = (const float*)d_in[2];
    const float* uemb      = (const float*)d_in[3];
    const float* iemb      = (const float*)d_in[4];
    const float* Wgc       = (const float*)d_in[5];
    const float* bgc       = (const float*)d_in[6];
    const float* Wbi       = (const float*)d_in[7];
    const float* bbi       = (const float*)d_in[8];
    float* out = (float*)d_out;

    char* p = (char*)d_ws;
    auto alloc = [&](size_t bytes) { char* r = p; p += (bytes + 255) & ~(size_t)255; return r; };
    int*   counts = (int*)alloc((size_t)NN * 4);
    int*   offs   = (int*)alloc((size_t)(NN + 1) * 4);
    int*   bsum   = (int*)alloc((size_t)NB * 4);
    int2*  pair   = (int2*)alloc((size_t)NE * 8);
    float* ego    = (float*)alloc((size_t)NN * DD * 4);
    float* side   = (float*)alloc((size_t)NN * DD * 4);
    unsigned short* rank = (unsigned short*)alloc((size_t)NE * 2);

    hipMemsetAsync(counts, 0, (size_t)NN * 4, stream);
    init_kernel<<<(NN * DD + 255) / 256, 256, 0, stream>>>(uemb, iemb, ego, out);
    hist_kernel<<<(NE + 255) / 256, 256, 0, stream>>>(edge_dst, counts, rank);
    scanA_kernel<<<NB, 256, 0, stream>>>(counts, bsum);
    scanB_kernel<<<1, 256, 0, stream>>>(bsum, offs);
    scanC_kernel<<<NB, 256, 0, stream>>>(counts, bsum, offs);
    fill_kernel<<<(NE + 255) / 256, 256, 0, stream>>>(edge_src, edge_dst, edge_vals, offs, rank, pair);

    for (int l = 0; l < NL; ++l) {
        spmm_kernel<<<(NN * 64 + 255) / 256, 256, 0, stream>>>(offs, pair, ego, side);
        update_kernel<<<UPD_GRID, UPD_TPB, 0, stream>>>(
            side, ego, Wgc + l * DD * DD, bgc + l * DD, Wbi + l * DD * DD, bbi + l * DD,
            out, l);
    }
}

// Round 6
// 874.593 us; speedup vs baseline: 2.0052x; 2.0052x over previous
//
#include <hip/hip_runtime.h>

#define NU 50000
#define NI 100000
#define NN 150000
#define NE 2400000
#define DD 64
#define NL 3
#define CHUNK 1024
#define NB ((NN + CHUNK - 1) / CHUNK)   // 147 scan blocks

// ---- init: ego = concat(user_emb, item_emb); out[:, 0:64] = ego (layer-0, un-normalized)
__global__ void init_kernel(const float* __restrict__ uemb, const float* __restrict__ iemb,
                            float* __restrict__ ego, float* __restrict__ out) {
    int i = blockIdx.x * blockDim.x + threadIdx.x;
    if (i >= NN * DD) return;
    int n = i >> 6, d = i & 63;
    float v = (n < NU) ? uemb[i] : iemb[i - NU * DD];
    ego[i] = v;
    out[n * (DD * (NL + 1)) + d] = v;
}

// ---- CSR build: histogram of dst + per-edge rank (the atomic's return value,
// which fill would otherwise have to re-derive with a second atomic round-trip)
__global__ void hist_kernel(const int* __restrict__ dst, int* __restrict__ counts,
                            unsigned short* __restrict__ rank) {
    int e = blockIdx.x * blockDim.x + threadIdx.x;
    if (e < NE) {
        int r = atomicAdd(&counts[dst[e]], 1);
        rank[e] = (unsigned short)r;   // mean degree 16; 65535 cap unreachable
    }
}

// ---- scan stage A: per-block (1024-elem chunk) totals
__global__ void scanA_kernel(const int* __restrict__ counts, int* __restrict__ bsum) {
    __shared__ int sh[256];
    int t = threadIdx.x, b = blockIdx.x;
    int base = b * CHUNK + t * 4;
    int s = 0;
#pragma unroll
    for (int i = 0; i < 4; ++i) { int idx = base + i; if (idx < NN) s += counts[idx]; }
    sh[t] = s; __syncthreads();
    for (int off = 128; off > 0; off >>= 1) {
        if (t < off) sh[t] += sh[t + off];
        __syncthreads();
    }
    if (t == 0) bsum[b] = sh[0];
}

// ---- scan stage B: exclusive scan of the NB(=147) block sums, one block
__global__ void scanB_kernel(int* __restrict__ bsum, int* __restrict__ offs) {
    __shared__ int sh[256];
    int t = threadIdx.x;
    int v = (t < NB) ? bsum[t] : 0;
    sh[t] = v; __syncthreads();
    for (int off = 1; off < 256; off <<= 1) {
        int add = (t >= off) ? sh[t - off] : 0;
        __syncthreads();
        sh[t] += add;
        __syncthreads();
    }
    if (t < NB) bsum[t] = sh[t] - v;          // exclusive block offset
    if (t == NB - 1) offs[NN] = sh[t];        // total == NE
}

// ---- scan stage C: full exclusive scan -> offs
__global__ void scanC_kernel(const int* __restrict__ counts, const int* __restrict__ bsum,
                             int* __restrict__ offs) {
    __shared__ int sh[256];
    int t = threadIdx.x, b = blockIdx.x;
    int base = b * CHUNK + t * 4;
    int c[4]; int tsum = 0;
#pragma unroll
    for (int i = 0; i < 4; ++i) { int idx = base + i; c[i] = (idx < NN) ? counts[idx] : 0; tsum += c[i]; }
    sh[t] = tsum; __syncthreads();
    for (int off = 1; off < 256; off <<= 1) {
        int add = (t >= off) ? sh[t - off] : 0;
        __syncthreads();
        sh[t] += add;
        __syncthreads();
    }
    int excl = sh[t] - tsum + bsum[b];
#pragma unroll
    for (int i = 0; i < 4; ++i) {
        int idx = base + i;
        if (idx < NN) offs[idx] = excl;
        excl += c[i];
    }
}

// ---- CSR fill: atomic-free. pos = offs[dst] + rank (rank captured in hist).
// Pure sequential reads + one scatter store; no TCC round-trip dependency.
__global__ void fill_kernel(const int* __restrict__ src, const int* __restrict__ dst,
                            const float* __restrict__ vals, const int* __restrict__ offs,
                            const unsigned short* __restrict__ rank, int2* __restrict__ pair) {
    int e = blockIdx.x * blockDim.x + threadIdx.x;
    if (e >= NE) return;
    int d = dst[e];
    int pos = offs[d] + (int)rank[e];
    pair[pos] = make_int2(src[e], __float_as_int(vals[e]));
}

// ---- gather SpMM: one wave per node; 4 edges per iteration, float4 per lane.
// Pair loads for iteration i+1 are issued before iteration i's row gathers,
// breaking the pair-load -> dependent-gather serial chain.
__global__ __launch_bounds__(256) void spmm_kernel(
        const int* __restrict__ offs, const int2* __restrict__ pair,
        const float* __restrict__ ego, float* __restrict__ side) {
    int gid = blockIdx.x * blockDim.x + threadIdx.x;
    int node = gid >> 6;
    if (node >= NN) return;
    int lane = threadIdx.x & 63;
    int sub = lane >> 4;       // which of the 4 edges
    int dq  = lane & 15;       // which dim-quad of the row
    int beg = offs[node], end = offs[node + 1];
    float4 acc = make_float4(0.f, 0.f, 0.f, 0.f);
    if (beg < end) {
        int idx0 = beg + sub;
        int2 p = pair[idx0 < end ? idx0 : end - 1];
        for (int i = beg; i < end; i += 4) {
            int2 pn = p;
            int ni = i + 4;
            if (ni < end) {
                int nidx = ni + sub;
                pn = pair[nidx < end ? nidx : end - 1];   // prefetch next quad
            }
            float w = (i + sub < end) ? __int_as_float(p.y) : 0.f;
            float4 v = ((const float4*)(ego + (size_t)p.x * DD))[dq];
            acc.x = fmaf(w, v.x, acc.x);
            acc.y = fmaf(w, v.y, acc.y);
            acc.z = fmaf(w, v.z, acc.z);
            acc.w = fmaf(w, v.w, acc.w);
            p = pn;
        }
    }
    acc.x += __shfl_xor(acc.x, 16); acc.y += __shfl_xor(acc.y, 16);
    acc.z += __shfl_xor(acc.z, 16); acc.w += __shfl_xor(acc.w, 16);
    acc.x += __shfl_xor(acc.x, 32); acc.y += __shfl_xor(acc.y, 32);
    acc.z += __shfl_xor(acc.z, 32); acc.w += __shfl_xor(acc.w, 32);
    if (sub == 0) ((float4*)(side + (size_t)node * DD))[dq] = acc;
}

// ---- update: W-in-VGPR outer-product (round-2 proven form).
// Lane j holds {Wg[j][k], Wb[j][k]} in 128 VGPRs. The k-loop MUST be fully
// unrolled so w[k] is compile-time-indexed (rule #20: runtime-indexed
// ext_vector arrays demote to scratch -> round-5's 1.24 GB FETCH regression
// came from '#pragma unroll 8' here). Per wave, 2 node rows staged in LDS;
// uniform-address ds_read_b64 broadcasts feed packed fma. Next pair's global
// loads issued before the k-loop (software pipeline). launch_bounds(256,3)
// gives the register headroom that makes the full unroll spill-free.
typedef float v2f __attribute__((ext_vector_type(2)));
#define UPD_TPB 256
#define UPD_GRID 1024
#define NPAIR (NN / 2)          // 75000, exact (no tail)

__global__ __launch_bounds__(UPD_TPB, 3) void update_kernel(
        const float* __restrict__ side, float* __restrict__ ego,
        const float* __restrict__ Wg, const float* __restrict__ bg,
        const float* __restrict__ Wb, const float* __restrict__ bb,
        float* __restrict__ out, int layer) {
    __shared__ v2f sm[UPD_TPB / 64][2][DD];   // per-wave private: 2 nodes x 64 dims
    int tid = threadIdx.x;
    int lane = tid & 63;
    int wid = tid >> 6;

    // lane j's interleaved W rows -> 128 VGPRs
    v2f w[DD];
    {
        const float4* g4 = (const float4*)(Wg + lane * DD);
        const float4* b4 = (const float4*)(Wb + lane * DD);
#pragma unroll
        for (int k4 = 0; k4 < 16; ++k4) {
            float4 a = g4[k4], b = b4[k4];
            w[4 * k4 + 0] = (v2f){a.x, b.x};
            w[4 * k4 + 1] = (v2f){a.y, b.y};
            w[4 * k4 + 2] = (v2f){a.z, b.z};
            w[4 * k4 + 3] = (v2f){a.w, b.w};
        }
    }
    v2f bias = {bg[lane], bb[lane]};

    const int nwaves = UPD_GRID * (UPD_TPB / 64);
    int g = blockIdx.x * (UPD_TPB / 64) + wid;
    if (g >= NPAIR) return;

    // prologue: load first pair's rows (coalesced, lane k holds dim k)
    float s0 = side[(size_t)(2 * g) * DD + lane];
    float s1 = side[(size_t)(2 * g + 1) * DD + lane];
    float e0 = ego[(size_t)(2 * g) * DD + lane];
    float e1 = ego[(size_t)(2 * g + 1) * DD + lane];

    while (true) {
        // stage current pair into LDS as {s, m=s*ego}
        sm[wid][0][lane] = (v2f){s0, s0 * e0};
        sm[wid][1][lane] = (v2f){s1, s1 * e1};

        int gn = g + nwaves;
        bool more = gn < NPAIR;
        int gl = more ? gn : g;   // last iter: harmless dead reload of current
        // issue next pair's loads; latency hides under the k-loop below
        s0 = side[(size_t)(2 * gl) * DD + lane];
        s1 = side[(size_t)(2 * gl + 1) * DD + lane];
        e0 = ego[(size_t)(2 * gl) * DD + lane];
        e1 = ego[(size_t)(2 * gl + 1) * DD + lane];

        v2f acc0 = bias, acc1 = bias;
#pragma unroll
        for (int k = 0; k < DD; ++k) {
            v2f a = sm[wid][0][k];   // uniform-address ds_read_b64 broadcast
            v2f b = sm[wid][1][k];
            acc0 = __builtin_elementwise_fma(a, w[k], acc0);
            acc1 = __builtin_elementwise_fma(b, w[k], acc1);
        }

        float ag0 = acc0.x, ab0 = acc0.y, ag1 = acc1.x, ab1 = acc1.y;
        ag0 = (ag0 > 0.f) ? ag0 : 0.01f * ag0;
        ab0 = (ab0 > 0.f) ? ab0 : 0.01f * ab0;
        ag1 = (ag1 > 0.f) ? ag1 : 0.01f * ag1;
        ab1 = (ab1 > 0.f) ? ab1 : 0.01f * ab1;
        float v0 = ag0 + ab0, v1 = ag1 + ab1;
        float sq0 = v0 * v0, sq1 = v1 * v1;
        // two interleaved 64-lane butterfly reductions
#pragma unroll
        for (int off = 1; off < 64; off <<= 1) {
            sq0 += __shfl_xor(sq0, off);
            sq1 += __shfl_xor(sq1, off);
        }
        float r0 = 1.f / fmaxf(sqrtf(sq0), 1e-12f);
        float r1 = 1.f / fmaxf(sqrtf(sq1), 1e-12f);
        int n0 = 2 * g;
        ego[(size_t)n0 * DD + lane] = v0;
        ego[(size_t)(n0 + 1) * DD + lane] = v1;
        out[(size_t)n0 * (DD * (NL + 1)) + (layer + 1) * DD + lane] = v0 * r0;
        out[(size_t)(n0 + 1) * (DD * (NL + 1)) + (layer + 1) * DD + lane] = v1 * r1;

        if (!more) break;
        g = gn;
    }
}

extern "C" void kernel_launch(void* const* d_in, const int* in_sizes, int n_in,
                              void* d_out, int out_size, void* d_ws, size_t ws_size,
                              hipStream_t stream) {
    const int*   edge_src  = (const int*)d_in[0];
    const int*   edge_dst  = (const int*)d_in[1];
    const float* edge_vals = (const float*)d_in[2];
    const float* uemb      = (const float*)d_in[3];
    const float* iemb      = (const float*)d_in[4];
    const float* Wgc       = (const float*)d_in[5];
    const float* bgc       = (const float*)d_in[6];
    const float* Wbi       = (const float*)d_in[7];
    const float* bbi       = (const float*)d_in[8];
    float* out = (float*)d_out;

    char* p = (char*)d_ws;
    auto alloc = [&](size_t bytes) { char* r = p; p += (bytes + 255) & ~(size_t)255; return r; };
    int*   counts = (int*)alloc((size_t)NN * 4);
    int*   offs   = (int*)alloc((size_t)(NN + 1) * 4);
    int*   bsum   = (int*)alloc((size_t)NB * 4);
    int2*  pair   = (int2*)alloc((size_t)NE * 8);
    float* ego    = (float*)alloc((size_t)NN * DD * 4);
    float* side   = (float*)alloc((size_t)NN * DD * 4);
    unsigned short* rank = (unsigned short*)alloc((size_t)NE * 2);

    hipMemsetAsync(counts, 0, (size_t)NN * 4, stream);
    init_kernel<<<(NN * DD + 255) / 256, 256, 0, stream>>>(uemb, iemb, ego, out);
    hist_kernel<<<(NE + 255) / 256, 256, 0, stream>>>(edge_dst, counts, rank);
    scanA_kernel<<<NB, 256, 0, stream>>>(counts, bsum);
    scanB_kernel<<<1, 256, 0, stream>>>(bsum, offs);
    scanC_kernel<<<NB, 256, 0, stream>>>(counts, bsum, offs);
    fill_kernel<<<(NE + 255) / 256, 256, 0, stream>>>(edge_src, edge_dst, edge_vals, offs, rank, pair);

    for (int l = 0; l < NL; ++l) {
        spmm_kernel<<<(NN * 64 + 255) / 256, 256, 0, stream>>>(offs, pair, ego, side);
        update_kernel<<<UPD_GRID, UPD_TPB, 0, stream>>>(
            side, ego, Wgc + l * DD * DD, bgc + l * DD, Wbi + l * DD * DD, bbi + l * DD,
            out, l);
    }
}